// Round 2
// baseline (1111.763 us; speedup 1.0000x reference)
//
#include <hip/hip_runtime.h>

#define H_DIM 1024
#define F_DIM 2048
#define NE 16
#define NG 4
#define EPG_C 4
#define NTOK 4096
#define NROWS 16384           // total (token,expert) rows: always exactly TOPK*NTOK
#define HID_ROWS (NROWS + 128) // pad: GEMM2 A-tiles may read up to 127 rows past the end
#define TB 8

using bf16x8 = __attribute__((ext_vector_type(8))) short;
using f32x4  = __attribute__((ext_vector_type(4))) float;

// ---------------- scalar helpers ----------------
__device__ __forceinline__ float gelu_f(float v) {
    return 0.5f * v * (1.0f + erff(v * 0.70710678118654752440f));
}
__device__ __forceinline__ unsigned short f2bf(float f) {   // RNE
    unsigned int u = __float_as_uint(f);
    u += 0x7FFFu + ((u >> 16) & 1u);
    return (unsigned short)(u >> 16);
}
__device__ __forceinline__ float bf2f(unsigned short s) {
    return __uint_as_float(((unsigned int)s) << 16);
}
__device__ __forceinline__ void split2(float v, unsigned short& hi, unsigned short& lo) {
    hi = f2bf(v);
    lo = f2bf(v - bf2f(hi));
}
__device__ __forceinline__ float wave_red_sum(float v) {
    #pragma unroll
    for (int off = 32; off > 0; off >>= 1) v += __shfl_down(v, off, 64);
    return v;
}
__device__ __forceinline__ void gld16(const void* g, void* l) {
    // async global->LDS, 16B/lane; LDS dest is wave-uniform base + lane*16
    __builtin_amdgcn_global_load_lds(
        (const __attribute__((address_space(1))) unsigned int*)g,
        (__attribute__((address_space(3))) unsigned int*)l, 16, 0, 0);
}

// ---------------- small kernels ----------------
__global__ __launch_bounds__(256) void zero_kernel(float* __restrict__ out, int n,
                                                   int* __restrict__ counts) {
    int i = blockIdx.x * blockDim.x + threadIdx.x;
    int stride = gridDim.x * blockDim.x;
    for (; i < n; i += stride) out[i] = 0.0f;
    if (blockIdx.x == 0 && threadIdx.x < NE) counts[threadIdx.x] = 0;
}

__global__ __launch_bounds__(256) void splitx_kernel(const float* __restrict__ x,
                                                     unsigned short* __restrict__ xh,
                                                     unsigned short* __restrict__ xl, int n4) {
    int i = blockIdx.x * blockDim.x + threadIdx.x;
    int stride = gridDim.x * blockDim.x;
    for (; i < n4; i += stride) {
        float4 v = ((const float4*)x)[i];
        ushort4 h, l;
        split2(v.x, h.x, l.x); split2(v.y, h.y, l.y);
        split2(v.z, h.z, l.z); split2(v.w, h.w, l.w);
        ((ushort4*)xh)[i] = h;
        ((ushort4*)xl)[i] = l;
    }
}

// W[e][K][N] fp32 -> Wt_hi/lo[e][N][K] bf16 (k-contiguous, as MFMA B-operand needs)
__global__ __launch_bounds__(256) void splitT_kernel(const float* __restrict__ W,
                                                     unsigned short* __restrict__ Th,
                                                     unsigned short* __restrict__ Tl,
                                                     int K, int N) {
    __shared__ float st[64][65];
    int e = blockIdx.z, kt = blockIdx.y, ntile = blockIdx.x;
    const float* src = W + (size_t)e * K * N + (size_t)kt * 64 * N + (size_t)ntile * 64;
    int t = threadIdx.x;
    int tr = t >> 4, tc = t & 15;
    #pragma unroll
    for (int i = 0; i < 4; ++i) {
        int row = tr + i * 16;
        float4 v = *(const float4*)(src + (size_t)row * N + tc * 4);
        st[row][tc * 4 + 0] = v.x; st[row][tc * 4 + 1] = v.y;
        st[row][tc * 4 + 2] = v.z; st[row][tc * 4 + 3] = v.w;
    }
    __syncthreads();
    unsigned short* dh = Th + (size_t)e * N * K + (size_t)ntile * 64 * K + kt * 64;
    unsigned short* dl = Tl + (size_t)e * N * K + (size_t)ntile * 64 * K + kt * 64;
    #pragma unroll
    for (int i = 0; i < 4; ++i) {
        int nl = tr + i * 16;
        ushort4 h4, l4;
        float v0 = st[tc * 4 + 0][nl], v1 = st[tc * 4 + 1][nl];
        float v2 = st[tc * 4 + 2][nl], v3 = st[tc * 4 + 3][nl];
        split2(v0, h4.x, l4.x); split2(v1, h4.y, l4.y);
        split2(v2, h4.z, l4.z); split2(v3, h4.w, l4.w);
        *(ushort4*)(dh + (size_t)nl * K + tc * 4) = h4;
        *(ushort4*)(dl + (size_t)nl * K + tc * 4) = l4;
    }
}

// ---------------- gate (round-1, unchanged) ----------------
__global__ __launch_bounds__(256) void gate_kernel(
    const float* __restrict__ x, const float* __restrict__ Wg, const float* __restrict__ bg,
    const float* __restrict__ Wr, const float* __restrict__ br,
    const float* __restrict__ Wc1, const float* __restrict__ bc1,
    const float* __restrict__ Wc2, const float* __restrict__ bc2,
    const float* __restrict__ priority,
    int* __restrict__ counts, int* __restrict__ tok_list, float* __restrict__ wt_list)
{
    __shared__ float xs[TB][H_DIM];
    __shared__ float c1s[TB][256];
    __shared__ float lg_s[TB][20];
    __shared__ float conf_s[TB];

    const int tid = threadIdx.x;
    const int t0 = blockIdx.x * TB;

    {
        const float4* xv = (const float4*)(x + (size_t)t0 * H_DIM);
        float4* xsv = (float4*)&xs[0][0];
        #pragma unroll
        for (int i = 0; i < (TB * H_DIM / 4) / 256; ++i) xsv[tid + i * 256] = xv[tid + i * 256];
    }
    __syncthreads();

    {
        float acc[TB];
        #pragma unroll
        for (int t = 0; t < TB; ++t) acc[t] = 0.f;
        for (int k = 0; k < H_DIM; k += 4) {
            float w0 = Wc1[(k + 0) * 256 + tid];
            float w1 = Wc1[(k + 1) * 256 + tid];
            float w2 = Wc1[(k + 2) * 256 + tid];
            float w3 = Wc1[(k + 3) * 256 + tid];
            #pragma unroll
            for (int t = 0; t < TB; ++t) {
                float4 xv4 = *(const float4*)&xs[t][k];
                acc[t] += xv4.x * w0 + xv4.y * w1 + xv4.z * w2 + xv4.w * w3;
            }
        }
        float b = bc1[tid];
        #pragma unroll
        for (int t = 0; t < TB; ++t) c1s[t][tid] = gelu_f(acc[t] + b);
    }
    __syncthreads();

    const int wid = tid >> 6;
    const int lane = tid & 63;

    for (int t = wid; t < TB; t += 4) {
        float p = 0.f;
        #pragma unroll
        for (int j = 0; j < 4; ++j) {
            int idx = lane + 64 * j;
            p += c1s[t][idx] * Wc2[idx];
        }
        p = wave_red_sum(p);
        if (lane == 0) conf_s[t] = 1.0f / (1.0f + expf(-(p + bc2[0])));
    }

    for (int task = wid; task < TB * 20; task += 4) {
        int t = task / 20;
        int d = task % 20;
        float p = 0.f;
        if (d < NG) {
            #pragma unroll
            for (int j = 0; j < H_DIM / 64; ++j) {
                int k = lane + 64 * j;
                p += xs[t][k] * Wg[k * NG + d];
            }
        } else {
            const float* wr = Wr + (size_t)(d - NG) * H_DIM;
            #pragma unroll
            for (int j = 0; j < H_DIM / 64; ++j) {
                int k = lane + 64 * j;
                p += xs[t][k] * wr[k];
            }
        }
        p = wave_red_sum(p);
        if (lane == 0) lg_s[t][d] = p;
    }
    __syncthreads();

    if (tid < TB) {
        int t = tid;
        int token = t0 + t;
        float conf = conf_s[t];

        float gl[NG], gp[NG];
        float mg = -1e30f;
        #pragma unroll
        for (int i = 0; i < NG; ++i) { gl[i] = lg_s[t][i] + bg[i]; mg = fmaxf(mg, gl[i]); }
        float sg = 0.f;
        #pragma unroll
        for (int i = 0; i < NG; ++i) { gp[i] = expf(gl[i] - mg); sg += gp[i]; }
        #pragma unroll
        for (int i = 0; i < NG; ++i) gp[i] /= sg;

        int g0 = 0;
        for (int i = 1; i < NG; ++i) if (gp[i] > gp[g0]) g0 = i;
        int g1 = -1;
        for (int i = 0; i < NG; ++i) { if (i == g0) continue; if (g1 < 0 || gp[i] > gp[g1]) g1 = i; }

        float sc[NE];
        #pragma unroll
        for (int i = 0; i < NE; ++i) sc[i] = 0.f;
        int gids[2] = {g0, g1};
        float tgp[2] = {gp[g0], gp[g1]};
        for (int s = 0; s < 2; ++s) {
            int gg = gids[s];
            float l[EPG_C];
            float pm = -1e30f;
            #pragma unroll
            for (int e2 = 0; e2 < EPG_C; ++e2) {
                int ge = gg * EPG_C + e2;
                l[e2] = (lg_s[t][NG + ge] + br[ge]) * priority[ge];
                pm = fmaxf(pm, l[e2]);
            }
            float ps = 0.f;
            #pragma unroll
            for (int e2 = 0; e2 < EPG_C; ++e2) { l[e2] = expf(l[e2] - pm); ps += l[e2]; }
            #pragma unroll
            for (int e2 = 0; e2 < EPG_C; ++e2) {
                float p = l[e2] / ps;
                p = p * conf + (1.0f - conf) * 0.25f;
                sc[gg * EPG_C + e2] = p * tgp[s];
            }
        }
        float ssum = 0.f;
        #pragma unroll
        for (int i = 0; i < NE; ++i) ssum += sc[i];
        ssum += 1e-9f;
        #pragma unroll
        for (int i = 0; i < NE; ++i) sc[i] /= ssum;

        bool used[NE];
        #pragma unroll
        for (int i = 0; i < NE; ++i) used[i] = false;
        for (int kk = 0; kk < 4; ++kk) {
            int best = -1; float bv = -1e30f;
            for (int i = 0; i < NE; ++i) if (!used[i] && sc[i] > bv) { bv = sc[i]; best = i; }
            used[best] = true;
            int pos = atomicAdd(&counts[best], 1);
            tok_list[best * NTOK + pos] = token;
            wt_list[best * NTOK + pos] = bv;
        }
    }
}

__global__ void scan_kernel(const int* __restrict__ counts, int* __restrict__ offsets) {
    if (threadIdx.x == 0 && blockIdx.x == 0) {
        int s = 0;
        for (int e = 0; e < NE; ++e) { offsets[e] = s; s += counts[e]; }
    }
}

// ---------------- MFMA grouped GEMM, split-bf16 (hi/lo), 128x128 tile, BK=64 ----------------
// A rows gathered per expert; B pre-transposed [e][n][k]. LDS: linear dest + inverse-swizzled
// global source + XOR-swizzled ds_read (chunk ^= row&7) per rule #21.
template<int KD, int ND, bool G1>
__global__ __launch_bounds__(256, 2) void gemm_mfma(
    const unsigned short* __restrict__ A_hi, const unsigned short* __restrict__ A_lo,
    const unsigned short* __restrict__ Bt_hi, const unsigned short* __restrict__ Bt_lo,
    const float* __restrict__ bias,
    const int* __restrict__ counts, const int* __restrict__ offsets,
    const int* __restrict__ tok_list, const float* __restrict__ wt_list,
    unsigned short* __restrict__ Chi, unsigned short* __restrict__ Clo,
    float* __restrict__ outp)
{
    constexpr int NT = ND / 128;
    const int MT = NTOK / 128;
    int bx = blockIdx.x;
    int e   = bx / (MT * NT);
    int rem = bx % (MT * NT);
    int mt = rem / NT, nt = rem % NT;
    int cnt = counts[e];
    if (mt * 128 >= cnt) return;
    int base = offsets[e];

    __shared__ unsigned short sm[4 * 128 * 64];   // A_hi | A_lo | B_hi | B_lo, 64 KiB
    unsigned short* smA_hi = sm;
    unsigned short* smA_lo = sm + 128 * 64;
    unsigned short* smB_hi = sm + 2 * 128 * 64;
    unsigned short* smB_lo = sm + 3 * 128 * 64;

    const int tid = threadIdx.x;
    const int lane = tid & 63;
    const int wid = tid >> 6;
    const int wr = wid >> 1, wc = wid & 1;
    const int l7 = lane & 7, l15 = lane & 15, lg = lane >> 4;
    const int srow = lane >> 3;                 // staging: row within 8-row window
    const int schunk = (lane & 7) ^ srow;       // staging: inverse-swizzled source chunk

    // per-lane A row offsets (elements) for the 4 staging instructions this wave issues
    int ro_[4];
    size_t bo_[4];
    const size_t bbase = (size_t)e * ND * KD + (size_t)nt * 128 * KD;
    #pragma unroll
    for (int i = 0; i < 4; ++i) {
        int rloc = wid * 32 + i * 8 + srow;     // 0..127 across waves
        if (G1) {
            int r = min(mt * 128 + rloc, cnt - 1);
            ro_[i] = tok_list[e * NTOK + r] * KD;
        } else {
            ro_[i] = (base + mt * 128 + rloc) * KD;   // hid is padded; no clamp needed
        }
        bo_[i] = bbase + (size_t)rloc * KD;
    }

    f32x4 acc[4][4];
    #pragma unroll
    for (int m = 0; m < 4; ++m)
        #pragma unroll
        for (int n = 0; n < 4; ++n)
            #pragma unroll
            for (int j = 0; j < 4; ++j) acc[m][n][j] = 0.0f;

    for (int ks = 0; ks < KD / 64; ++ks) {
        __syncthreads();                        // previous compute done; LDS reusable
        const int k0 = ks * 64;
        #pragma unroll
        for (int i = 0; i < 4; ++i) {
            const int R0 = wid * 32 + i * 8;
            gld16(A_hi + ro_[i] + k0 + schunk * 8, smA_hi + R0 * 64);
            gld16(A_lo + ro_[i] + k0 + schunk * 8, smA_lo + R0 * 64);
            gld16(Bt_hi + bo_[i] + k0 + schunk * 8, smB_hi + R0 * 64);
            gld16(Bt_lo + bo_[i] + k0 + schunk * 8, smB_lo + R0 * 64);
        }
        __syncthreads();                        // compiler drains vmcnt before s_barrier

        #pragma unroll
        for (int kk = 0; kk < 2; ++kk) {
            bf16x8 ah[4], al[4], bh[4], bl[4];
            #pragma unroll
            for (int m = 0; m < 4; ++m) {
                int row = wr * 64 + m * 16 + l15;
                int eo = row * 64 + (((kk * 4 + lg) ^ l7) * 8);
                ah[m] = *(const bf16x8*)(smA_hi + eo);
                al[m] = *(const bf16x8*)(smA_lo + eo);
            }
            #pragma unroll
            for (int n = 0; n < 4; ++n) {
                int row = wc * 64 + n * 16 + l15;
                int eo = row * 64 + (((kk * 4 + lg) ^ l7) * 8);
                bh[n] = *(const bf16x8*)(smB_hi + eo);
                bl[n] = *(const bf16x8*)(smB_lo + eo);
            }
            #pragma unroll
            for (int m = 0; m < 4; ++m)
                #pragma unroll
                for (int n = 0; n < 4; ++n) {
                    acc[m][n] = __builtin_amdgcn_mfma_f32_16x16x32_bf16(ah[m], bh[n], acc[m][n], 0, 0, 0);
                    acc[m][n] = __builtin_amdgcn_mfma_f32_16x16x32_bf16(ah[m], bl[n], acc[m][n], 0, 0, 0);
                    acc[m][n] = __builtin_amdgcn_mfma_f32_16x16x32_bf16(al[m], bh[n], acc[m][n], 0, 0, 0);
                }
        }
    }

    // epilogue: C/D layout col = lane&15, row = (lane>>4)*4 + reg  [m89-verified]
    #pragma unroll
    for (int m = 0; m < 4; ++m) {
        #pragma unroll
        for (int reg = 0; reg < 4; ++reg) {
            int row = mt * 128 + wr * 64 + m * 16 + lg * 4 + reg;
            if (row >= cnt) continue;
            if (G1) {
                #pragma unroll
                for (int n = 0; n < 4; ++n) {
                    int col = nt * 128 + wc * 64 + n * 16 + l15;
                    float v = gelu_f(acc[m][n][reg] + bias[e * ND + col]);
                    unsigned short hi, lo;
                    split2(v, hi, lo);
                    size_t o = (size_t)(base + row) * ND + col;
                    Chi[o] = hi;
                    Clo[o] = lo;
                }
            } else {
                int tok = tok_list[e * NTOK + row];
                float w = wt_list[e * NTOK + row];
                #pragma unroll
                for (int n = 0; n < 4; ++n) {
                    int col = nt * 128 + wc * 64 + n * 16 + l15;
                    float v = (acc[m][n][reg] + bias[e * ND + col]) * w;
                    atomicAdd(&outp[(size_t)tok * ND + col], v);
                }
            }
        }
    }
}

// ---------------- fp32 fallback GEMMs (round-1) — used only if ws too small ----------------
__global__ __launch_bounds__(256) void gemm1_f32(
    const float* __restrict__ x, const float* __restrict__ W1, const float* __restrict__ b1,
    const int* __restrict__ counts, const int* __restrict__ offsets,
    const int* __restrict__ tok_list, float* __restrict__ hid)
{
    const int NT = F_DIM / 64;
    const int MT = NTOK / 64;
    int bx = blockIdx.x;
    int e   = bx / (MT * NT);
    int rem = bx % (MT * NT);
    int mt = rem / NT;
    int nt = rem % NT;
    int cnt = counts[e];
    if (mt * 64 >= cnt) return;

    __shared__ float As[16][68];
    __shared__ float Bs[16][64];

    int tid = threadIdx.x;
    int aRow = tid >> 2, aSeg = tid & 3;
    int bRow = tid >> 4, bSeg = tid & 15;
    int ty = tid >> 4, tx = tid & 15;

    int gRow = mt * 64 + aRow;
    bool aValid = gRow < cnt;
    const float* aPtr = x;
    if (aValid) {
        int tok = tok_list[e * NTOK + gRow];
        aPtr = x + (size_t)tok * H_DIM + aSeg * 4;
    }
    const float* bPtr = W1 + (size_t)e * H_DIM * F_DIM + (size_t)bRow * F_DIM + nt * 64 + bSeg * 4;

    float acc[4][4];
    #pragma unroll
    for (int i = 0; i < 4; ++i)
        #pragma unroll
        for (int j = 0; j < 4; ++j) acc[i][j] = 0.f;

    for (int k0 = 0; k0 < H_DIM; k0 += 16) {
        float4 a4 = make_float4(0.f, 0.f, 0.f, 0.f);
        if (aValid) a4 = *(const float4*)(aPtr + k0);
        float4 b4 = *(const float4*)(bPtr + (size_t)k0 * F_DIM);
        __syncthreads();
        As[aSeg * 4 + 0][aRow] = a4.x;
        As[aSeg * 4 + 1][aRow] = a4.y;
        As[aSeg * 4 + 2][aRow] = a4.z;
        As[aSeg * 4 + 3][aRow] = a4.w;
        *(float4*)&Bs[bRow][bSeg * 4] = b4;
        __syncthreads();
        #pragma unroll
        for (int kk = 0; kk < 16; ++kk) {
            float4 av = *(const float4*)&As[kk][ty * 4];
            float4 bv = *(const float4*)&Bs[kk][tx * 4];
            float a[4] = {av.x, av.y, av.z, av.w};
            float b[4] = {bv.x, bv.y, bv.z, bv.w};
            #pragma unroll
            for (int i = 0; i < 4; ++i)
                #pragma unroll
                for (int j = 0; j < 4; ++j)
                    acc[i][j] = fmaf(a[i], b[j], acc[i][j]);
        }
    }

    int base = offsets[e];
    #pragma unroll
    for (int i = 0; i < 4; ++i) {
        int r = mt * 64 + ty * 4 + i;
        if (r >= cnt) continue;
        size_t rowOff = (size_t)(base + r) * F_DIM;
        #pragma unroll
        for (int j = 0; j < 4; ++j) {
            int c = nt * 64 + tx * 4 + j;
            hid[rowOff + c] = gelu_f(acc[i][j] + b1[e * F_DIM + c]);
        }
    }
}

__global__ __launch_bounds__(256) void gemm2_f32(
    const float* __restrict__ hid, const float* __restrict__ W2, const float* __restrict__ b2,
    const int* __restrict__ counts, const int* __restrict__ offsets,
    const int* __restrict__ tok_list, const float* __restrict__ wt_list,
    float* __restrict__ out)
{
    const int NT = H_DIM / 64;
    const int MT = NTOK / 64;
    int bx = blockIdx.x;
    int e   = bx / (MT * NT);
    int rem = bx % (MT * NT);
    int mt = rem / NT;
    int nt = rem % NT;
    int cnt = counts[e];
    if (mt * 64 >= cnt) return;
    int base = offsets[e];

    __shared__ float As[16][68];
    __shared__ float Bs[16][64];

    int tid = threadIdx.x;
    int aRow = tid >> 2, aSeg = tid & 3;
    int bRow = tid >> 4, bSeg = tid & 15;
    int ty = tid >> 4, tx = tid & 15;

    int gRow = mt * 64 + aRow;
    bool aValid = gRow < cnt;
    const float* aPtr = hid;
    if (aValid) aPtr = hid + (size_t)(base + gRow) * F_DIM + aSeg * 4;
    const float* bPtr = W2 + (size_t)e * F_DIM * H_DIM + (size_t)bRow * H_DIM + nt * 64 + bSeg * 4;

    float acc[4][4];
    #pragma unroll
    for (int i = 0; i < 4; ++i)
        #pragma unroll
        for (int j = 0; j < 4; ++j) acc[i][j] = 0.f;

    for (int k0 = 0; k0 < F_DIM; k0 += 16) {
        float4 a4 = make_float4(0.f, 0.f, 0.f, 0.f);
        if (aValid) a4 = *(const float4*)(aPtr + k0);
        float4 b4 = *(const float4*)(bPtr + (size_t)k0 * H_DIM);
        __syncthreads();
        As[aSeg * 4 + 0][aRow] = a4.x;
        As[aSeg * 4 + 1][aRow] = a4.y;
        As[aSeg * 4 + 2][aRow] = a4.z;
        As[aSeg * 4 + 3][aRow] = a4.w;
        *(float4*)&Bs[bRow][bSeg * 4] = b4;
        __syncthreads();
        #pragma unroll
        for (int kk = 0; kk < 16; ++kk) {
            float4 av = *(const float4*)&As[kk][ty * 4];
            float4 bv = *(const float4*)&Bs[kk][tx * 4];
            float a[4] = {av.x, av.y, av.z, av.w};
            float b[4] = {bv.x, bv.y, bv.z, bv.w};
            #pragma unroll
            for (int i = 0; i < 4; ++i)
                #pragma unroll
                for (int j = 0; j < 4; ++j)
                    acc[i][j] = fmaf(a[i], b[j], acc[i][j]);
        }
    }

    #pragma unroll
    for (int i = 0; i < 4; ++i) {
        int r = mt * 64 + ty * 4 + i;
        if (r >= cnt) continue;
        int tok  = tok_list[e * NTOK + r];
        float w  = wt_list[e * NTOK + r];
        #pragma unroll
        for (int j = 0; j < 4; ++j) {
            int c = nt * 64 + tx * 4 + j;
            atomicAdd(&out[(size_t)tok * H_DIM + c], (acc[i][j] + b2[e * H_DIM + c]) * w);
        }
    }
}

// ---------------- host ----------------
// ws layout (MFMA path):
//   0        counts (64B) | 256 offsets | 512 tok_list 256K | 262656 wt_list 256K
//   1MiB     x_hi 8M | x_lo 8M                                  -> ends 17,825,792
//   17.0MB   hid_hi 16512*2048*2 | hid_lo                       -> ends 153,092,096
//   153.1MB  Wt_hi 64M | Wt_lo 64M (W1t for gemm1, reused as W2t)-> ends 287,309,824
#define OFF_COUNTS  0
#define OFF_OFFSETS 256
#define OFF_TOK     512
#define OFF_WTL     (512 + NE * NTOK * 4)
#define OFF_XH      (1ull << 20)
#define OFF_XL      (OFF_XH + (size_t)NTOK * H_DIM * 2)
#define OFF_HIDH    (OFF_XL + (size_t)NTOK * H_DIM * 2)
#define OFF_HIDL    (OFF_HIDH + (size_t)HID_ROWS * F_DIM * 2)
#define OFF_WTH     (OFF_HIDL + (size_t)HID_ROWS * F_DIM * 2)
#define OFF_WTLO    (OFF_WTH + (size_t)NE * H_DIM * F_DIM * 2)
#define WS_NEED     (OFF_WTLO + (size_t)NE * H_DIM * F_DIM * 2)

extern "C" void kernel_launch(void* const* d_in, const int* in_sizes, int n_in,
                              void* d_out, int out_size, void* d_ws, size_t ws_size,
                              hipStream_t stream)
{
    const float* x   = (const float*)d_in[0];
    const float* Wg  = (const float*)d_in[1];
    const float* bg  = (const float*)d_in[2];
    const float* Wr  = (const float*)d_in[3];
    const float* br  = (const float*)d_in[4];
    const float* Wc1 = (const float*)d_in[5];
    const float* bc1 = (const float*)d_in[6];
    const float* Wc2 = (const float*)d_in[7];
    const float* bc2 = (const float*)d_in[8];
    const float* pri = (const float*)d_in[9];
    const float* W1  = (const float*)d_in[10];
    const float* b1  = (const float*)d_in[11];
    const float* W2  = (const float*)d_in[12];
    const float* b2  = (const float*)d_in[13];
    float* out = (float*)d_out;

    char* ws = (char*)d_ws;
    int*   counts   = (int*)(ws + OFF_COUNTS);
    int*   offsets  = (int*)(ws + OFF_OFFSETS);
    int*   tok_list = (int*)(ws + OFF_TOK);
    float* wt_list  = (float*)(ws + OFF_WTL);

    zero_kernel<<<2048, 256, 0, stream>>>(out, out_size, counts);
    gate_kernel<<<NTOK / TB, 256, 0, stream>>>(x, Wg, bg, Wr, br, Wc1, bc1, Wc2, bc2, pri,
                                               counts, tok_list, wt_list);
    scan_kernel<<<1, 64, 0, stream>>>(counts, offsets);

    if (ws_size >= WS_NEED) {
        unsigned short* xh   = (unsigned short*)(ws + OFF_XH);
        unsigned short* xl   = (unsigned short*)(ws + OFF_XL);
        unsigned short* hidh = (unsigned short*)(ws + OFF_HIDH);
        unsigned short* hidl = (unsigned short*)(ws + OFF_HIDL);
        unsigned short* wth  = (unsigned short*)(ws + OFF_WTH);
        unsigned short* wtl  = (unsigned short*)(ws + OFF_WTLO);

        splitx_kernel<<<2048, 256, 0, stream>>>(x, xh, xl, NTOK * H_DIM / 4);
        splitT_kernel<<<dim3(F_DIM / 64, H_DIM / 64, NE), 256, 0, stream>>>(W1, wth, wtl,
                                                                            H_DIM, F_DIM);
        gemm_mfma<H_DIM, F_DIM, true><<<NE * (NTOK / 128) * (F_DIM / 128), 256, 0, stream>>>(
            xh, xl, wth, wtl, b1, counts, offsets, tok_list, wt_list, hidh, hidl, nullptr);
        splitT_kernel<<<dim3(H_DIM / 64, F_DIM / 64, NE), 256, 0, stream>>>(W2, wth, wtl,
                                                                            F_DIM, H_DIM);
        gemm_mfma<F_DIM, H_DIM, false><<<NE * (NTOK / 128) * (H_DIM / 128), 256, 0, stream>>>(
            hidh, hidl, wth, wtl, b2, counts, offsets, tok_list, wt_list, nullptr, nullptr, out);
    } else {
        float* hid = (float*)(ws + (1 << 20));
        gemm1_f32<<<NE * (NTOK / 64) * (F_DIM / 64), 256, 0, stream>>>(x, W1, b1, counts, offsets,
                                                                       tok_list, hid);
        gemm2_f32<<<NE * (NTOK / 64) * (H_DIM / 64), 256, 0, stream>>>(hid, W2, b2, counts, offsets,
                                                                       tok_list, wt_list, out);
    }
}